// Round 4
// baseline (435.835 us; speedup 1.0000x reference)
//
#include <hip/hip_runtime.h>

typedef _Float16 f16x8 __attribute__((ext_vector_type(8)));
typedef float f32x4 __attribute__((ext_vector_type(4)));

#define NB 8192
#define DD 32
#define PER 25

__device__ __forceinline__ float gelu_f(float x) {
    float x3 = x * x * x;
    return 0.5f * x * (1.0f + tanhf(0.7978845608028654f * (x + 0.044715f * x3)));
}
__device__ __forceinline__ float softplus_f(float x) {
    return (x > 20.0f) ? x : log1pf(expf(x));
}
// # hidden units with degree <= d (degs 1..8 have 9 units, 9..31 have 8)
__device__ __forceinline__ int cntf(int d) {
    return (d <= 0) ? 0 : ((d <= 8) ? 9 * d : 72 + 8 * (d - 8));
}
// original hidden index of degree-sorted position u
__device__ __forceinline__ int porig(int u) {
    int d = (u < 72) ? (u / 9 + 1) : ((u - 72) / 8 + 9);
    int s = (u < 72) ? (u % 9) : ((u - 72) % 8);
    return s * 31 + (d - 1);
}

// Pack all weights into MFMA B-fragment layout (f16, masks baked in, zero padding).
// B-frag for 16x16x32: lane l holds B[k][c] with c = l&15, k = (l>>4)*8 + j, j=0..7.
// W0F  [32 steps][64 lanes][8]            : Phase A, c = new-unit slot (deg=i), k = x dim
// W1F  [32][8 kt][64][8]                  : Phase B, c = new-unit slot, k = kt*32 + ...(h0 pos)
// WoutF[32][2 ct][8 kt][64][8]            : Phase C, c -> param ct*16+c, k = h1 pos
__global__ void prep_kernel(const float* __restrict__ W0, const float* __restrict__ b0,
                            const float* __restrict__ W1, const float* __restrict__ b1,
                            const float* __restrict__ Wout, const float* __restrict__ bout,
                            _Float16* __restrict__ W0F, _Float16* __restrict__ W1F,
                            _Float16* __restrict__ WoutF,
                            float* __restrict__ b0F, float* __restrict__ b1F,
                            float* __restrict__ boutF)
{
    const int total = 16384 + 131072 + 262144 + 512 + 512 + 1024;  // 411648
    for (int e = blockIdx.x * blockDim.x + threadIdx.x; e < total;
         e += gridDim.x * blockDim.x) {
        if (e < 16384) {
            int i = e >> 9, r = e & 511, lane = r >> 3, j = r & 7;
            int c = lane & 15, k = ((lane >> 4) << 3) + j;
            int nn = cntf(i) - cntf(i - 1);
            float v = 0.0f;
            if (c < nn && k < i) v = W0[k * 256 + (c * 31 + i - 1)];
            W0F[e] = (_Float16)v;
        } else if (e < 16384 + 131072) {
            int m = e - 16384;
            int i = m >> 12, r = m & 4095, kt = r >> 9, r2 = r & 511;
            int lane = r2 >> 3, j = r2 & 7;
            int c = lane & 15, kpos = kt * 32 + ((lane >> 4) << 3) + j;
            int nn = cntf(i) - cntf(i - 1), chi = cntf(i);
            float v = 0.0f;
            if (c < nn && kpos < chi) v = W1[porig(kpos) * 256 + (c * 31 + i - 1)];
            W1F[m] = (_Float16)v;
        } else if (e < 16384 + 131072 + 262144) {
            int m = e - (16384 + 131072);
            int i = m >> 13, r = m & 8191, ct = r >> 12, r2 = r & 4095;
            int kt = r2 >> 9, r3 = r2 & 511, lane = r3 >> 3, j = r3 & 7;
            int par = ct * 16 + (lane & 15), kpos = kt * 32 + ((lane >> 4) << 3) + j;
            int chi = cntf(i);
            float v = 0.0f;
            if (par < 25 && kpos < chi) v = Wout[(i * 25 + par) * 256 + porig(kpos)];
            WoutF[m] = (_Float16)v;
        } else if (e < 409600 + 512) {
            int m = e - 409600;
            int i = m >> 4, c = m & 15;
            int nn = cntf(i) - cntf(i - 1);
            b0F[m] = (c < nn) ? b0[c * 31 + i - 1] : 0.0f;
        } else if (e < 410112 + 512) {
            int m = e - 410112;
            int i = m >> 4, c = m & 15;
            int nn = cntf(i) - cntf(i - 1);
            b1F[m] = (c < nn) ? b1[c * 31 + i - 1] : 0.0f;
        } else {
            int m = e - 410624;
            int i = m >> 5, c = m & 31;
            boutF[m] = (c < 25) ? bout[i * 25 + c] : 0.0f;
        }
    }
}

// One wave per block; 16 rows per wave, all 32 AR steps, MACs on the matrix pipe.
__global__ __launch_bounds__(64) void inv_kernel(
    const float* __restrict__ z,
    const _Float16* __restrict__ W0F, const _Float16* __restrict__ W1F,
    const _Float16* __restrict__ WoutF,
    const float* __restrict__ b0F, const float* __restrict__ b1F,
    const float* __restrict__ boutF,
    const int* __restrict__ tstep_p,
    float* __restrict__ xout, float* __restrict__ ldj)
{
    __shared__ float zs[512];            // z tile  [16 rows][32]
    __shared__ float xs[512];            // x state [16 rows][32]
    __shared__ float ps[16 * 33];        // spline params per row (padded)
    __shared__ _Float16 snew[2][256];    // new-unit scratch [unit][row]

    const int l = threadIdx.x;
    const int c16 = l & 15;              // C/D col, B col, A row selector
    const int g = l >> 4;                // k-group
    const int row0 = blockIdx.x * 16;

    for (int idx = l; idx < 512; idx += 64) {
        zs[idx] = z[row0 * 32 + idx];
        xs[idx] = 0.0f;
    }

    f16x8 xfrag;                         // A-frag of x: row=c16, k=g*8+j
    f16x8 h0f[8], h1f[8];                // A-frags of h0/h1: 8 k-tiles
#pragma unroll
    for (int j = 0; j < 8; ++j) xfrag[j] = (_Float16)0.0f;
#pragma unroll
    for (int kt = 0; kt < 8; ++kt) {
#pragma unroll
        for (int j = 0; j < 8; ++j) { h0f[kt][j] = (_Float16)0.0f; h1f[kt][j] = (_Float16)0.0f; }
    }

    const float alpha = fminf(fmaxf(((float)(*tstep_p)) / 10000.0f, 0.0f), 1.0f);
    const float oma = 1.0f - alpha;
    const float dxoff = logf(expm1f(0.9999f));   // DX_OFF

    float ldreg = 0.0f;
    __syncthreads();

#pragma unroll 1
    for (int i = 0; i < DD; ++i) {
        const int clo = cntf(i - 1);
        const int chi = cntf(i);
        const int nn = chi - clo;        // 0 at i=0, else 8 or 9

        // ---- Phase A: h0_new(16 rows x <=9 units) = gelu(x @ W0_i) ----
        if (nn > 0) {
            f16x8 wa = *(const f16x8*)&W0F[(i * 64 + l) * 8];
            f32x4 acc;
#pragma unroll
            for (int q = 0; q < 4; ++q) acc[q] = 0.0f;
            acc = __builtin_amdgcn_mfma_f32_16x16x32_f16(xfrag, wa, acc, 0, 0, 0);
            float bb = b0F[i * 16 + c16];
#pragma unroll
            for (int q = 0; q < 4; ++q)
                snew[0][c16 * 16 + g * 4 + q] = (_Float16)gelu_f(acc[q] + bb);
        }
        __syncthreads();

        // fold new h0 units into A-frags (row=c16, k=kt*32+g*8+j)
        if (nn > 0) {
#pragma unroll
            for (int kt = 0; kt < 8; ++kt) {
                if (clo < (kt + 1) * 32 && chi > kt * 32) {   // uniform overlap test
#pragma unroll
                    for (int j = 0; j < 8; ++j) {
                        int k = kt * 32 + g * 8 + j;
                        bool use = (k >= clo) && (k < chi);
                        int off = use ? ((k - clo) * 16 + c16) : 0;
                        _Float16 v = snew[0][off];
                        if (use) h0f[kt][j] = v;
                    }
                }
            }
        }

        // ---- Phase B: h1_new = gelu(h0_prefix @ W1_i) ----
        if (nn > 0) {
            f32x4 acc;
#pragma unroll
            for (int q = 0; q < 4; ++q) acc[q] = 0.0f;
#pragma unroll
            for (int kt = 0; kt < 8; ++kt) {
                if (kt * 32 < chi) {
                    f16x8 wb = *(const f16x8*)&W1F[((i * 8 + kt) * 64 + l) * 8];
                    acc = __builtin_amdgcn_mfma_f32_16x16x32_f16(h0f[kt], wb, acc, 0, 0, 0);
                }
            }
            float bb = b1F[i * 16 + c16];
#pragma unroll
            for (int q = 0; q < 4; ++q)
                snew[1][c16 * 16 + g * 4 + q] = (_Float16)gelu_f(acc[q] + bb);
        }
        __syncthreads();

        // fold new h1 units into A-frags
        if (nn > 0) {
#pragma unroll
            for (int kt = 0; kt < 8; ++kt) {
                if (clo < (kt + 1) * 32 && chi > kt * 32) {
#pragma unroll
                    for (int j = 0; j < 8; ++j) {
                        int k = kt * 32 + g * 8 + j;
                        bool use = (k >= clo) && (k < chi);
                        int off = use ? ((k - clo) * 16 + c16) : 0;
                        _Float16 v = snew[1][off];
                        if (use) h1f[kt][j] = v;
                    }
                }
            }
        }

        // ---- Phase C: p(16 rows x 25) = h1_prefix @ Wout_i + b_out ----
#pragma unroll
        for (int ct = 0; ct < 2; ++ct) {
            f32x4 acc;
#pragma unroll
            for (int q = 0; q < 4; ++q) acc[q] = 0.0f;
#pragma unroll
            for (int kt = 0; kt < 8; ++kt) {
                if (kt * 32 < chi) {
                    f16x8 wc = *(const f16x8*)&WoutF[(((i * 2 + ct) * 8 + kt) * 64 + l) * 8];
                    acc = __builtin_amdgcn_mfma_f32_16x16x32_f16(h1f[kt], wc, acc, 0, 0, 0);
                }
            }
            float bo = boutF[i * 32 + ct * 16 + c16];
            if (ct * 16 + c16 < 25) {
#pragma unroll
                for (int q = 0; q < 4; ++q)
                    ps[(g * 4 + q) * 33 + ct * 16 + c16] = acc[q] + bo;
            }
        }
        __syncthreads();

        // ---- Spline inverse: serial per row on lanes 0..15 ----
        float xv_sel = 0.0f;
        if (l < 16) {
            const float* pp = &ps[l * 33];
            float pw[8], ph[8], pd[9];
#pragma unroll
            for (int q = 0; q < 8; ++q) pw[q] = pp[q];
#pragma unroll
            for (int q = 0; q < 8; ++q) ph[q] = pp[8 + q];
#pragma unroll
            for (int q = 0; q < 9; ++q) pd[q] = pp[16 + q];

            float wdt[8], hgt[8];
            {
                float m = pw[0];
#pragma unroll
                for (int q = 1; q < 8; ++q) m = fmaxf(m, pw[q]);
                float e[8], s = 0.f;
#pragma unroll
                for (int q = 0; q < 8; ++q) { e[q] = expf(pw[q] - m); s += e[q]; }
                float bw[8], sb = 0.f;
#pragma unroll
                for (int q = 0; q < 8; ++q) {
                    float lw = e[q] / s * 9.92f + 0.001f;
                    bw[q] = oma * 1.25f + alpha * lw;
                    sb += bw[q];
                }
                float sc = 10.0f / sb;
                float m2 = bw[0] * sc;
#pragma unroll
                for (int q = 0; q < 8; ++q) { bw[q] *= sc; m2 = fmaxf(m2, bw[q]); }
                float s2 = 0.f;
#pragma unroll
                for (int q = 0; q < 8; ++q) { e[q] = expf(bw[q] - m2); s2 += e[q]; }
#pragma unroll
                for (int q = 0; q < 8; ++q) wdt[q] = e[q] / s2 * 9.9992f + 1e-4f;
            }
            {
                float m = ph[0];
#pragma unroll
                for (int q = 1; q < 8; ++q) m = fmaxf(m, ph[q]);
                float e[8], s = 0.f;
#pragma unroll
                for (int q = 0; q < 8; ++q) { e[q] = expf(ph[q] - m); s += e[q]; }
                float bh[8], sb = 0.f;
#pragma unroll
                for (int q = 0; q < 8; ++q) {
                    float lh = e[q] / s * 9.92f + 0.001f;
                    bh[q] = oma * 1.25f + alpha * lh;
                    sb += bh[q];
                }
                float sc = 10.0f / sb;
                float m2 = bh[0] * sc;
#pragma unroll
                for (int q = 0; q < 8; ++q) { bh[q] *= sc; m2 = fmaxf(m2, bh[q]); }
                float s2 = 0.f;
#pragma unroll
                for (int q = 0; q < 8; ++q) { e[q] = expf(bh[q] - m2); s2 += e[q]; }
#pragma unroll
                for (int q = 0; q < 8; ++q) hgt[q] = e[q] / s2 * 9.9992f + 1e-4f;
            }
            float dd_[9];
#pragma unroll
            for (int q = 0; q < 9; ++q) {
                float ls = softplus_f(pd[q]) + 0.001f;
                float sl = oma + alpha * ls;
                dd_[q] = softplus_f(sl + dxoff) + 1e-4f;
            }
            float xp[9], yp[9];
            xp[0] = -5.0f; yp[0] = -5.0f;
            {
                float cx = 0.f, cy = 0.f;
#pragma unroll
                for (int q = 0; q < 8; ++q) {
                    cx += wdt[q]; xp[q + 1] = -5.0f + cx;
                    cy += hgt[q]; yp[q + 1] = -5.0f + cy;
                }
            }

            const float zi = zs[l * 32 + i];
            const bool inr = (zi >= -5.0f) && (zi <= 5.0f);
            const float yc = fminf(fmaxf(zi, -5.0f), 5.0f);

            float xk = xp[0], yk = yp[0], wk = wdt[0], hk = hgt[0], dk = dd_[0], dk1 = dd_[1];
#pragma unroll
            for (int q = 1; q < 8; ++q) {
                bool c = (yc >= yp[q]);
                xk = c ? xp[q] : xk;  yk = c ? yp[q] : yk;
                wk = c ? wdt[q] : wk; hk = c ? hgt[q] : hk;
                dk = c ? dd_[q] : dk; dk1 = c ? dd_[q + 1] : dk1;
            }

            float s_ = hk / wk;
            float tt = yc - yk;
            float coef = dk1 + dk - 2.0f * s_;
            float aa = hk * (s_ - dk) + tt * coef;
            float bb = hk * dk - tt * coef;
            float cc = -s_ * tt;
            float disc = bb * bb - 4.0f * aa * cc;
            float xi = 2.0f * cc / (-bb - sqrtf(disc));
            float xv = xi * wk + xk;
            float z1 = xi * (1.0f - xi);
            float den = s_ + coef * z1;
            float omxi = 1.0f - xi;
            float ld = -(2.0f * logf(s_) + logf(dk1 * xi * xi + 2.0f * s_ * z1 + dk * omxi * omxi)
                         - 2.0f * logf(den));

            xv_sel = inr ? xv : zi;
            ldreg += inr ? ld : 0.0f;
            xs[l * 32 + i] = xv_sel;
        }

        // broadcast new x_i into the x A-fragment (k == i)
        {
            float xnew = __shfl(xv_sel, c16);
            if (g == (i >> 3)) {
#pragma unroll
                for (int j = 0; j < 8; ++j)
                    if (j == (i & 7)) xfrag[j] = (_Float16)xnew;
            }
        }
        __syncthreads();
    }

    for (int idx = l; idx < 512; idx += 64)
        xout[row0 * 32 + idx] = xs[idx];
    if (l < 16) ldj[row0 + l] = ldreg;
}

extern "C" void kernel_launch(void* const* d_in, const int* in_sizes, int n_in,
                              void* d_out, int out_size, void* d_ws, size_t ws_size,
                              hipStream_t stream)
{
    const float* z    = (const float*)d_in[0];
    const float* W0   = (const float*)d_in[1];
    const float* b0   = (const float*)d_in[2];
    const float* W1   = (const float*)d_in[3];
    const float* b1   = (const float*)d_in[4];
    const float* Wout = (const float*)d_in[5];
    const float* bout = (const float*)d_in[6];
    const int* tstep  = (const int*)d_in[8];

    float* out  = (float*)d_out;
    float* xout = out;                 // x_fin, B x D
    float* ldj  = out + NB * DD;       // ldj, B

    _Float16* W0F   = (_Float16*)d_ws;            // 16384 halfs
    _Float16* W1F   = W0F + 16384;                // 131072 halfs
    _Float16* WoutF = W1F + 131072;               // 262144 halfs
    float* b0F  = (float*)(WoutF + 262144);       // 512 f32
    float* b1F  = b0F + 512;                      // 512 f32
    float* boutF = b1F + 512;                     // 1024 f32

    prep_kernel<<<1608, 256, 0, stream>>>(W0, b0, W1, b1, Wout, bout,
                                          W0F, W1F, WoutF, b0F, b1F, boutF);
    inv_kernel<<<NB / 16, 64, 0, stream>>>(z, W0F, W1F, WoutF, b0F, b1F, boutF,
                                           tstep, xout, ldj);
}

// Round 5
// 159.367 us; speedup vs baseline: 2.7348x; 2.7348x over previous
//
#include <hip/hip_runtime.h>

typedef _Float16 f16x8 __attribute__((ext_vector_type(8)));
typedef float f32x4 __attribute__((ext_vector_type(4)));

#define NB 8192
#define DD 32
#define PER 25

// wave-internal LDS fence (block == 1 wave): drain own LDS ops + stop reordering
#define FENCE() do { asm volatile("s_waitcnt lgkmcnt(0)" ::: "memory"); \
                     __builtin_amdgcn_sched_barrier(0); } while (0)

__device__ __forceinline__ float rcp_f(float x) { return __builtin_amdgcn_rcpf(x); }
__device__ __forceinline__ float gelu_f(float x) {
    // x * sigmoid(1.5957691*(x + 0.044715 x^3))  ==  tanh-form gelu
    float a = -1.5957691216057308f * (x + 0.044715f * x * x * x);
    return x * rcp_f(1.0f + __expf(a));
}
__device__ __forceinline__ float softplus_f(float x) {
    return (x > 20.0f) ? x : __logf(1.0f + __expf(x));
}
// # hidden units with degree <= d (degs 1..8 have 9 units, 9..31 have 8)
__device__ __forceinline__ int cntf(int d) {
    return (d <= 0) ? 0 : ((d <= 8) ? 9 * d : 72 + 8 * (d - 8));
}
// original hidden index of degree-sorted position u
__device__ __forceinline__ int porig(int u) {
    int d = (u < 72) ? (u / 9 + 1) : ((u - 72) / 8 + 9);
    int s = (u < 72) ? (u % 9) : ((u - 72) % 8);
    return s * 31 + (d - 1);
}

// Pack all weights into MFMA B-fragment layout (f16, masks baked in, zero padding).
// B-frag for 16x16x32: lane l holds B[k][c] with c = l&15, k = (l>>4)*8 + j, j=0..7.
__global__ void prep_kernel(const float* __restrict__ W0, const float* __restrict__ b0,
                            const float* __restrict__ W1, const float* __restrict__ b1,
                            const float* __restrict__ Wout, const float* __restrict__ bout,
                            _Float16* __restrict__ W0F, _Float16* __restrict__ W1F,
                            _Float16* __restrict__ WoutF,
                            float* __restrict__ b0F, float* __restrict__ b1F,
                            float* __restrict__ boutF)
{
    const int total = 16384 + 131072 + 262144 + 512 + 512 + 1024;  // 411648
    for (int e = blockIdx.x * blockDim.x + threadIdx.x; e < total;
         e += gridDim.x * blockDim.x) {
        if (e < 16384) {
            int i = e >> 9, r = e & 511, lane = r >> 3, j = r & 7;
            int c = lane & 15, k = ((lane >> 4) << 3) + j;
            int nn = cntf(i) - cntf(i - 1);
            float v = 0.0f;
            if (c < nn && k < i) v = W0[k * 256 + (c * 31 + i - 1)];
            W0F[e] = (_Float16)v;
        } else if (e < 16384 + 131072) {
            int m = e - 16384;
            int i = m >> 12, r = m & 4095, kt = r >> 9, r2 = r & 511;
            int lane = r2 >> 3, j = r2 & 7;
            int c = lane & 15, kpos = kt * 32 + ((lane >> 4) << 3) + j;
            int nn = cntf(i) - cntf(i - 1), chi = cntf(i);
            float v = 0.0f;
            if (c < nn && kpos < chi) v = W1[porig(kpos) * 256 + (c * 31 + i - 1)];
            W1F[m] = (_Float16)v;
        } else if (e < 16384 + 131072 + 262144) {
            int m = e - (16384 + 131072);
            int i = m >> 13, r = m & 8191, ct = r >> 12, r2 = r & 4095;
            int kt = r2 >> 9, r3 = r2 & 511, lane = r3 >> 3, j = r3 & 7;
            int par = ct * 16 + (lane & 15), kpos = kt * 32 + ((lane >> 4) << 3) + j;
            int chi = cntf(i);
            float v = 0.0f;
            if (par < 25 && kpos < chi) v = Wout[(i * 25 + par) * 256 + porig(kpos)];
            WoutF[m] = (_Float16)v;
        } else if (e < 409600 + 512) {
            int m = e - 409600;
            int i = m >> 4, c = m & 15;
            int nn = cntf(i) - cntf(i - 1);
            b0F[m] = (c < nn) ? b0[c * 31 + i - 1] : 0.0f;
        } else if (e < 410112 + 512) {
            int m = e - 410112;
            int i = m >> 4, c = m & 15;
            int nn = cntf(i) - cntf(i - 1);
            b1F[m] = (c < nn) ? b1[c * 31 + i - 1] : 0.0f;
        } else {
            int m = e - 410624;
            int i = m >> 5, c = m & 31;
            boutF[m] = (c < 25) ? bout[i * 25 + c] : 0.0f;
        }
    }
}

// One wave per block; 16 rows per wave, all 32 AR steps, MACs on the matrix pipe.
__global__ __launch_bounds__(64, 1) void inv_kernel(
    const float* __restrict__ z,
    const _Float16* __restrict__ W0F, const _Float16* __restrict__ W1F,
    const _Float16* __restrict__ WoutF,
    const float* __restrict__ b0F, const float* __restrict__ b1F,
    const float* __restrict__ boutF,
    const int* __restrict__ tstep_p,
    float* __restrict__ xout, float* __restrict__ ldj)
{
    __shared__ float zs[16 * 33];        // z tile  [16 rows][33] (padded)
    __shared__ float xs[16 * 33];        // x state [16 rows][33] (padded)
    __shared__ float ps[16 * 33];        // spline params per row (padded)
    __shared__ _Float16 snew[2][160];    // new-unit scratch [unit][row], stride 17

    const int l = threadIdx.x;
    const int c16 = l & 15;              // C/D col, B col, A row selector
    const int g = l >> 4;                // k-group
    const int row0 = blockIdx.x * 16;

    for (int idx = l; idx < 512; idx += 64) {
        int r = idx >> 5, c = idx & 31;
        zs[r * 33 + c] = z[row0 * 32 + idx];
    }

    f16x8 xfrag;                         // A-frag of x: row=c16, k=g*8+j
    f16x8 h0f[8], h1f[8];                // A-frags of h0/h1: 8 k-tiles
#pragma unroll
    for (int j = 0; j < 8; ++j) xfrag[j] = (_Float16)0.0f;
#pragma unroll
    for (int kt = 0; kt < 8; ++kt) {
#pragma unroll
        for (int j = 0; j < 8; ++j) { h0f[kt][j] = (_Float16)0.0f; h1f[kt][j] = (_Float16)0.0f; }
    }

    const float alpha = fminf(fmaxf(((float)(*tstep_p)) / 10000.0f, 0.0f), 1.0f);
    const float oma = 1.0f - alpha;
    const float dxoff = logf(expm1f(0.9999f));   // DX_OFF (once, precise)

    float ldreg = 0.0f;
    FENCE();

#pragma unroll 1
    for (int i = 0; i < DD; ++i) {
        const int clo = cntf(i - 1);
        const int chi = cntf(i);
        const int nn = chi - clo;        // 0 at i=0, else 8 or 9

        // ---- hoisted weight-frag loads for this step (unconditional; zero-padded) ----
        const f16x8 wa_r = *(const f16x8*)&W0F[i * 512 + l * 8];
        f16x8 wb_r[8], wc_r[2][8];
#pragma unroll
        for (int kt = 0; kt < 8; ++kt)
            wb_r[kt] = *(const f16x8*)&W1F[i * 4096 + kt * 512 + l * 8];
#pragma unroll
        for (int ct = 0; ct < 2; ++ct)
#pragma unroll
            for (int kt = 0; kt < 8; ++kt)
                wc_r[ct][kt] = *(const f16x8*)&WoutF[i * 8192 + ct * 4096 + kt * 512 + l * 8];

        // ---- Phase A: h0_new(16 rows x <=9 units) = gelu(x @ W0_i) ----
        if (nn > 0) {
            f32x4 acc;
#pragma unroll
            for (int q = 0; q < 4; ++q) acc[q] = 0.0f;
            acc = __builtin_amdgcn_mfma_f32_16x16x32_f16(xfrag, wa_r, acc, 0, 0, 0);
            float bb = b0F[i * 16 + c16];
#pragma unroll
            for (int q = 0; q < 4; ++q)
                snew[0][c16 * 17 + g * 4 + q] = (_Float16)gelu_f(acc[q] + bb);
        }
        FENCE();

        // fold new h0 units into A-frags (row=c16, k=kt*32+g*8+j)
        if (nn > 0) {
#pragma unroll
            for (int kt = 0; kt < 8; ++kt) {
                if (clo < (kt + 1) * 32 && chi > kt * 32) {   // uniform overlap test
#pragma unroll
                    for (int j = 0; j < 8; ++j) {
                        int k = kt * 32 + g * 8 + j;
                        bool use = (k >= clo) && (k < chi);
                        int off = use ? ((k - clo) * 17 + c16) : 0;
                        _Float16 v = snew[0][off];
                        if (use) h0f[kt][j] = v;
                    }
                }
            }
        }
        FENCE();

        // ---- Phase B: h1_new = gelu(h0_prefix @ W1_i) ----
        if (nn > 0) {
            f32x4 acc;
#pragma unroll
            for (int q = 0; q < 4; ++q) acc[q] = 0.0f;
#pragma unroll
            for (int kt = 0; kt < 8; ++kt) {
                if (kt * 32 < chi)
                    acc = __builtin_amdgcn_mfma_f32_16x16x32_f16(h0f[kt], wb_r[kt], acc, 0, 0, 0);
            }
            float bb = b1F[i * 16 + c16];
#pragma unroll
            for (int q = 0; q < 4; ++q)
                snew[1][c16 * 17 + g * 4 + q] = (_Float16)gelu_f(acc[q] + bb);
        }
        FENCE();

        // fold new h1 units into A-frags
        if (nn > 0) {
#pragma unroll
            for (int kt = 0; kt < 8; ++kt) {
                if (clo < (kt + 1) * 32 && chi > kt * 32) {
#pragma unroll
                    for (int j = 0; j < 8; ++j) {
                        int k = kt * 32 + g * 8 + j;
                        bool use = (k >= clo) && (k < chi);
                        int off = use ? ((k - clo) * 17 + c16) : 0;
                        _Float16 v = snew[1][off];
                        if (use) h1f[kt][j] = v;
                    }
                }
            }
        }
        FENCE();

        // ---- Phase C: p(16 rows x 25) = h1_prefix @ Wout_i + b_out ----
#pragma unroll
        for (int ct = 0; ct < 2; ++ct) {
            f32x4 acc;
#pragma unroll
            for (int q = 0; q < 4; ++q) acc[q] = 0.0f;
#pragma unroll
            for (int kt = 0; kt < 8; ++kt) {
                if (kt * 32 < chi)
                    acc = __builtin_amdgcn_mfma_f32_16x16x32_f16(h1f[kt], wc_r[ct][kt], acc, 0, 0, 0);
            }
            float bo = boutF[i * 32 + ct * 16 + c16];
            if (ct * 16 + c16 < 25) {
#pragma unroll
                for (int q = 0; q < 4; ++q)
                    ps[(g * 4 + q) * 33 + ct * 16 + c16] = acc[q] + bo;
            }
        }
        FENCE();

        // ---- Spline inverse: serial per row on lanes 0..15 (fast transcendentals) ----
        float xv_sel = 0.0f;
        if (l < 16) {
            const float* pp = &ps[l * 33];
            float pw[8], ph[8], pd[9];
#pragma unroll
            for (int q = 0; q < 8; ++q) pw[q] = pp[q];
#pragma unroll
            for (int q = 0; q < 8; ++q) ph[q] = pp[8 + q];
#pragma unroll
            for (int q = 0; q < 9; ++q) pd[q] = pp[16 + q];

            float wdt[8], hgt[8];
            {
                float m = fmaxf(fmaxf(fmaxf(pw[0], pw[1]), fmaxf(pw[2], pw[3])),
                                fmaxf(fmaxf(pw[4], pw[5]), fmaxf(pw[6], pw[7])));
                float e[8], s = 0.f;
#pragma unroll
                for (int q = 0; q < 8; ++q) { e[q] = __expf(pw[q] - m); s += e[q]; }
                float rs = rcp_f(s);
                float bw[8], sb = 0.f;
#pragma unroll
                for (int q = 0; q < 8; ++q) {
                    float lw = e[q] * rs * 9.92f + 0.001f;
                    bw[q] = oma * 1.25f + alpha * lw;
                    sb += bw[q];
                }
                float sc = 10.0f * rcp_f(sb);
                float m2 = bw[0] * sc;
#pragma unroll
                for (int q = 0; q < 8; ++q) { bw[q] *= sc; m2 = fmaxf(m2, bw[q]); }
                float s2 = 0.f;
#pragma unroll
                for (int q = 0; q < 8; ++q) { e[q] = __expf(bw[q] - m2); s2 += e[q]; }
                float rs2 = rcp_f(s2);
#pragma unroll
                for (int q = 0; q < 8; ++q) wdt[q] = e[q] * rs2 * 9.9992f + 1e-4f;
            }
            {
                float m = fmaxf(fmaxf(fmaxf(ph[0], ph[1]), fmaxf(ph[2], ph[3])),
                                fmaxf(fmaxf(ph[4], ph[5]), fmaxf(ph[6], ph[7])));
                float e[8], s = 0.f;
#pragma unroll
                for (int q = 0; q < 8; ++q) { e[q] = __expf(ph[q] - m); s += e[q]; }
                float rs = rcp_f(s);
                float bh[8], sb = 0.f;
#pragma unroll
                for (int q = 0; q < 8; ++q) {
                    float lh = e[q] * rs * 9.92f + 0.001f;
                    bh[q] = oma * 1.25f + alpha * lh;
                    sb += bh[q];
                }
                float sc = 10.0f * rcp_f(sb);
                float m2 = bh[0] * sc;
#pragma unroll
                for (int q = 0; q < 8; ++q) { bh[q] *= sc; m2 = fmaxf(m2, bh[q]); }
                float s2 = 0.f;
#pragma unroll
                for (int q = 0; q < 8; ++q) { e[q] = __expf(bh[q] - m2); s2 += e[q]; }
                float rs2 = rcp_f(s2);
#pragma unroll
                for (int q = 0; q < 8; ++q) hgt[q] = e[q] * rs2 * 9.9992f + 1e-4f;
            }
            float dd_[9];
#pragma unroll
            for (int q = 0; q < 9; ++q) {
                float ls = softplus_f(pd[q]) + 0.001f;
                float sl = oma + alpha * ls;
                dd_[q] = softplus_f(sl + dxoff) + 1e-4f;
            }
            float xp[9], yp[9];
            xp[0] = -5.0f; yp[0] = -5.0f;
            {
                float cx = 0.f, cy = 0.f;
#pragma unroll
                for (int q = 0; q < 8; ++q) {
                    cx += wdt[q]; xp[q + 1] = -5.0f + cx;
                    cy += hgt[q]; yp[q + 1] = -5.0f + cy;
                }
            }

            const float zi = zs[l * 33 + i];
            const bool inr = (zi >= -5.0f) && (zi <= 5.0f);
            const float yc = fminf(fmaxf(zi, -5.0f), 5.0f);

            float xk = xp[0], yk = yp[0], wk = wdt[0], hk = hgt[0], dk = dd_[0], dk1 = dd_[1];
#pragma unroll
            for (int q = 1; q < 8; ++q) {
                bool c = (yc >= yp[q]);
                xk = c ? xp[q] : xk;  yk = c ? yp[q] : yk;
                wk = c ? wdt[q] : wk; hk = c ? hgt[q] : hk;
                dk = c ? dd_[q] : dk; dk1 = c ? dd_[q + 1] : dk1;
            }

            float s_ = hk * rcp_f(wk);
            float tt = yc - yk;
            float coef = dk1 + dk - 2.0f * s_;
            float aa = hk * (s_ - dk) + tt * coef;
            float bb = hk * dk - tt * coef;
            float cc = -s_ * tt;
            float disc = bb * bb - 4.0f * aa * cc;
            float xi = 2.0f * cc * rcp_f(-bb - __builtin_amdgcn_sqrtf(disc));
            float xv = xi * wk + xk;
            float z1 = xi * (1.0f - xi);
            float den = s_ + coef * z1;
            float omxi = 1.0f - xi;
            float ld = -(2.0f * __logf(s_) +
                         __logf(dk1 * xi * xi + 2.0f * s_ * z1 + dk * omxi * omxi)
                         - 2.0f * __logf(den));

            xv_sel = inr ? xv : zi;
            ldreg += inr ? ld : 0.0f;
            xs[l * 33 + i] = xv_sel;
        }

        // broadcast new x_i into the x A-fragment (k == i)
        {
            float xnew = __shfl(xv_sel, c16);
            if (g == (i >> 3)) {
#pragma unroll
                for (int j = 0; j < 8; ++j)
                    if (j == (i & 7)) xfrag[j] = (_Float16)xnew;
            }
        }
        FENCE();
    }

    for (int idx = l; idx < 512; idx += 64) {
        int r = idx >> 5, c = idx & 31;
        xout[row0 * 32 + idx] = xs[r * 33 + c];
    }
    if (l < 16) ldj[row0 + l] = ldreg;
}

extern "C" void kernel_launch(void* const* d_in, const int* in_sizes, int n_in,
                              void* d_out, int out_size, void* d_ws, size_t ws_size,
                              hipStream_t stream)
{
    const float* z    = (const float*)d_in[0];
    const float* W0   = (const float*)d_in[1];
    const float* b0   = (const float*)d_in[2];
    const float* W1   = (const float*)d_in[3];
    const float* b1   = (const float*)d_in[4];
    const float* Wout = (const float*)d_in[5];
    const float* bout = (const float*)d_in[6];
    const int* tstep  = (const int*)d_in[8];

    float* out  = (float*)d_out;
    float* xout = out;                 // x_fin, B x D
    float* ldj  = out + NB * DD;       // ldj, B

    _Float16* W0F   = (_Float16*)d_ws;            // 16384 halfs
    _Float16* W1F   = W0F + 16384;                // 131072 halfs
    _Float16* WoutF = W1F + 131072;               // 262144 halfs
    float* b0F  = (float*)(WoutF + 262144);       // 512 f32
    float* b1F  = b0F + 512;                      // 512 f32
    float* boutF = b1F + 512;                     // 1024 f32

    prep_kernel<<<1608, 256, 0, stream>>>(W0, b0, W1, b1, Wout, bout,
                                          W0F, W1F, WoutF, b0F, b1F, boutF);
    inv_kernel<<<NB / 16, 64, 0, stream>>>(z, W0F, W1F, WoutF, b0F, b1F, boutF,
                                           tstep, xout, ldj);
}

// Round 6
// 134.790 us; speedup vs baseline: 3.2334x; 1.1823x over previous
//
#include <hip/hip_runtime.h>

typedef _Float16 f16x8 __attribute__((ext_vector_type(8)));
typedef float f32x4 __attribute__((ext_vector_type(4)));

#define NB 8192
#define DD 32
#define PER 25

// Compiler-only ordering fence. A wave's DS (LDS) instructions are processed
// in program order by the LDS pipe, so same-wave write->read handoffs need no
// hardware waitcnt (lgkmcnt only gates register hazards, which the compiler
// inserts automatically). We only need to stop compiler reordering.
#define FENCE() do { asm volatile("" ::: "memory"); \
                     __builtin_amdgcn_sched_barrier(0); } while (0)

__device__ __forceinline__ float rcp_f(float x) { return __builtin_amdgcn_rcpf(x); }
__device__ __forceinline__ float gelu_f(float x) {
    float a = -1.5957691216057308f * (x + 0.044715f * x * x * x);
    return x * rcp_f(1.0f + __expf(a));
}
__device__ __forceinline__ float softplus_f(float x) {
    return (x > 20.0f) ? x : __logf(1.0f + __expf(x));
}
// # hidden units with degree <= d (degs 1..8 have 9 units, 9..31 have 8)
__device__ __forceinline__ int cntf(int d) {
    return (d <= 0) ? 0 : ((d <= 8) ? 9 * d : 72 + 8 * (d - 8));
}
// original hidden index of degree-sorted position u
__device__ __forceinline__ int porig(int u) {
    int d = (u < 72) ? (u / 9 + 1) : ((u - 72) / 8 + 9);
    int s = (u < 72) ? (u % 9) : ((u - 72) % 8);
    return s * 31 + (d - 1);
}

// Pack all weights into MFMA B-fragment layout (f16, masks baked in, zero padding).
// B-frag for 16x16x32: lane l holds B[k][c] with c = l&15, k = (l>>4)*8 + j, j=0..7.
__global__ void prep_kernel(const float* __restrict__ W0, const float* __restrict__ b0,
                            const float* __restrict__ W1, const float* __restrict__ b1,
                            const float* __restrict__ Wout, const float* __restrict__ bout,
                            _Float16* __restrict__ W0F, _Float16* __restrict__ W1F,
                            _Float16* __restrict__ WoutF,
                            float* __restrict__ b0F, float* __restrict__ b1F,
                            float* __restrict__ boutF)
{
    const int total = 16384 + 131072 + 262144 + 512 + 512 + 1024;  // 411648
    for (int e = blockIdx.x * blockDim.x + threadIdx.x; e < total;
         e += gridDim.x * blockDim.x) {
        if (e < 16384) {
            int i = e >> 9, r = e & 511, lane = r >> 3, j = r & 7;
            int c = lane & 15, k = ((lane >> 4) << 3) + j;
            int nn = cntf(i) - cntf(i - 1);
            float v = 0.0f;
            if (c < nn && k < i) v = W0[k * 256 + (c * 31 + i - 1)];
            W0F[e] = (_Float16)v;
        } else if (e < 16384 + 131072) {
            int m = e - 16384;
            int i = m >> 12, r = m & 4095, kt = r >> 9, r2 = r & 511;
            int lane = r2 >> 3, j = r2 & 7;
            int c = lane & 15, kpos = kt * 32 + ((lane >> 4) << 3) + j;
            int nn = cntf(i) - cntf(i - 1), chi = cntf(i);
            float v = 0.0f;
            if (c < nn && kpos < chi) v = W1[porig(kpos) * 256 + (c * 31 + i - 1)];
            W1F[m] = (_Float16)v;
        } else if (e < 16384 + 131072 + 262144) {
            int m = e - (16384 + 131072);
            int i = m >> 13, r = m & 8191, ct = r >> 12, r2 = r & 4095;
            int kt = r2 >> 9, r3 = r2 & 511, lane = r3 >> 3, j = r3 & 7;
            int par = ct * 16 + (lane & 15), kpos = kt * 32 + ((lane >> 4) << 3) + j;
            int chi = cntf(i);
            float v = 0.0f;
            if (par < 25 && kpos < chi) v = Wout[(i * 25 + par) * 256 + porig(kpos)];
            WoutF[m] = (_Float16)v;
        } else if (e < 409600 + 512) {
            int m = e - 409600;
            int i = m >> 4, c = m & 15;
            int nn = cntf(i) - cntf(i - 1);
            b0F[m] = (c < nn) ? b0[c * 31 + i - 1] : 0.0f;
        } else if (e < 410112 + 512) {
            int m = e - 410112;
            int i = m >> 4, c = m & 15;
            int nn = cntf(i) - cntf(i - 1);
            b1F[m] = (c < nn) ? b1[c * 31 + i - 1] : 0.0f;
        } else {
            int m = e - 410624;
            int i = m >> 5, c = m & 31;
            boutF[m] = (c < 25) ? bout[i * 25 + c] : 0.0f;
        }
    }
}

// One wave per block; 16 rows per wave, all 32 AR steps, MACs on the matrix pipe.
__global__ __launch_bounds__(64, 1) void inv_kernel(
    const float* __restrict__ z,
    const _Float16* __restrict__ W0F, const _Float16* __restrict__ W1F,
    const _Float16* __restrict__ WoutF,
    const float* __restrict__ b0F, const float* __restrict__ b1F,
    const float* __restrict__ boutF,
    const int* __restrict__ tstep_p,
    float* __restrict__ xout, float* __restrict__ ldj)
{
    __shared__ float zs[16 * 33];        // z tile  [16 rows][33] (padded)
    __shared__ float xs[16 * 33];        // x state [16 rows][33] (padded)
    __shared__ float ps[16 * 33];        // spline params per row (padded)
    __shared__ _Float16 snew[2][160];    // new-unit scratch [unit][row], stride 17

    const int l = threadIdx.x;
    const int c16 = l & 15;              // C/D col, B col, A row selector
    const int g = l >> 4;                // k-group
    const int row0 = blockIdx.x * 16;

    for (int idx = l; idx < 512; idx += 64) {
        int r = idx >> 5, c = idx & 31;
        zs[r * 33 + c] = z[row0 * 32 + idx];
    }

    f16x8 xfrag;                         // A-frag of x: row=c16, k=g*8+j
    f16x8 h0f[8], h1f[8];                // A-frags of h0/h1: 8 k-tiles
#pragma unroll
    for (int j = 0; j < 8; ++j) xfrag[j] = (_Float16)0.0f;
#pragma unroll
    for (int kt = 0; kt < 8; ++kt) {
#pragma unroll
        for (int j = 0; j < 8; ++j) { h0f[kt][j] = (_Float16)0.0f; h1f[kt][j] = (_Float16)0.0f; }
    }

    const float alpha = fminf(fmaxf(((float)(*tstep_p)) / 10000.0f, 0.0f), 1.0f);
    const float oma = 1.0f - alpha;
    const float dxoff = logf(expm1f(0.9999f));   // DX_OFF (once, precise)

    float ldreg = 0.0f;

    // double-buffered Phase-A weights + biases (the only latency-exposed loads)
    f16x8 wa2[2];
    float b0v2[2], b1v2[2], boA2[2], boB2[2];
    wa2[0] = *(const f16x8*)&W0F[l * 8];
    b0v2[0] = b0F[c16];
    b1v2[0] = b1F[c16];
    boA2[0] = boutF[c16];
    boB2[0] = boutF[16 + c16];

    FENCE();

#pragma unroll 1
    for (int ib = 0; ib < DD; ib += 2) {
#pragma unroll
        for (int ph = 0; ph < 2; ++ph) {
            const int i = ib + ph;
            const int clo = cntf(i - 1);
            const int chi = cntf(i);
            const int nn = chi - clo;        // 0 at i=0, else 8 or 9
            const int ip = (i + 1 < DD) ? (i + 1) : (DD - 1);

            // prefetch next step's A-weights + biases into the other buffer
            wa2[ph ^ 1] = *(const f16x8*)&W0F[ip * 512 + l * 8];
            b0v2[ph ^ 1] = b0F[ip * 16 + c16];
            b1v2[ph ^ 1] = b1F[ip * 16 + c16];
            boA2[ph ^ 1] = boutF[ip * 32 + c16];
            boB2[ph ^ 1] = boutF[ip * 32 + 16 + c16];

            // this step's B/C weight frags (first use is far enough to hide L2)
            f16x8 wb_r[8], wc_r[2][8];
#pragma unroll
            for (int kt = 0; kt < 8; ++kt)
                wb_r[kt] = *(const f16x8*)&W1F[i * 4096 + kt * 512 + l * 8];
#pragma unroll
            for (int ct = 0; ct < 2; ++ct)
#pragma unroll
                for (int kt = 0; kt < 8; ++kt)
                    wc_r[ct][kt] = *(const f16x8*)&WoutF[i * 8192 + ct * 4096 + kt * 512 + l * 8];

            // ---- Phase A: h0_new(16 rows x <=9 units) = gelu(x @ W0_i) ----
            if (nn > 0) {
                f32x4 acc;
#pragma unroll
                for (int q = 0; q < 4; ++q) acc[q] = 0.0f;
                acc = __builtin_amdgcn_mfma_f32_16x16x32_f16(xfrag, wa2[ph], acc, 0, 0, 0);
                float bb = b0v2[ph];
#pragma unroll
                for (int q = 0; q < 4; ++q)
                    snew[0][c16 * 17 + g * 4 + q] = (_Float16)gelu_f(acc[q] + bb);
            }
            FENCE();

            // fold new h0 units into A-frags (row=c16, k=kt*32+g*8+j)
            if (nn > 0) {
#pragma unroll
                for (int kt = 0; kt < 8; ++kt) {
                    if (clo < (kt + 1) * 32 && chi > kt * 32) {   // uniform overlap test
#pragma unroll
                        for (int j = 0; j < 8; ++j) {
                            int k = kt * 32 + g * 8 + j;
                            bool use = (k >= clo) && (k < chi);
                            int off = use ? ((k - clo) * 17 + c16) : 0;
                            _Float16 v = snew[0][off];
                            if (use) h0f[kt][j] = v;
                        }
                    }
                }
            }
            FENCE();

            // ---- Phase B: h1_new = gelu(h0_prefix @ W1_i) ----
            if (nn > 0) {
                f32x4 acc;
#pragma unroll
                for (int q = 0; q < 4; ++q) acc[q] = 0.0f;
#pragma unroll
                for (int kt = 0; kt < 8; ++kt) {
                    if (kt * 32 < chi)
                        acc = __builtin_amdgcn_mfma_f32_16x16x32_f16(h0f[kt], wb_r[kt], acc, 0, 0, 0);
                }
                float bb = b1v2[ph];
#pragma unroll
                for (int q = 0; q < 4; ++q)
                    snew[1][c16 * 17 + g * 4 + q] = (_Float16)gelu_f(acc[q] + bb);
            }
            FENCE();

            // fold new h1 units into A-frags
            if (nn > 0) {
#pragma unroll
                for (int kt = 0; kt < 8; ++kt) {
                    if (clo < (kt + 1) * 32 && chi > kt * 32) {
#pragma unroll
                        for (int j = 0; j < 8; ++j) {
                            int k = kt * 32 + g * 8 + j;
                            bool use = (k >= clo) && (k < chi);
                            int off = use ? ((k - clo) * 17 + c16) : 0;
                            _Float16 v = snew[1][off];
                            if (use) h1f[kt][j] = v;
                        }
                    }
                }
            }
            FENCE();

            // ---- Phase C: p(16 rows x 25) = h1_prefix @ Wout_i + b_out ----
#pragma unroll
            for (int ct = 0; ct < 2; ++ct) {
                f32x4 acc;
#pragma unroll
                for (int q = 0; q < 4; ++q) acc[q] = 0.0f;
#pragma unroll
                for (int kt = 0; kt < 8; ++kt) {
                    if (kt * 32 < chi)
                        acc = __builtin_amdgcn_mfma_f32_16x16x32_f16(h1f[kt], wc_r[ct][kt], acc, 0, 0, 0);
                }
                float bo = (ct == 0) ? boA2[ph] : boB2[ph];
                if (ct * 16 + c16 < 25) {
#pragma unroll
                    for (int q = 0; q < 4; ++q)
                        ps[(g * 4 + q) * 33 + ct * 16 + c16] = acc[q] + bo;
                }
            }
            FENCE();

            // ---- Spline inverse: 4 lanes per row, all 64 lanes active ----
            float xv_sel;
            {
                const int r4 = l >> 2;          // row 0..15
                const int p  = l & 3;           // sub-lane in quad
                const int qb = l & ~3;          // quad base lane

                const float* bp = &ps[r4 * 33];
                float w_a = bp[p],      w_b = bp[4 + p];
                float h_a = bp[8 + p],  h_b = bp[12 + p];
                float d_a = bp[16 + p], d_b = bp[20 + p], d_cin = bp[24];
                const float zi = zs[r4 * 33 + i];

                auto qsum = [](float v) {
                    v += __shfl_xor(v, 1); v += __shfl_xor(v, 2); return v;
                };
                auto qmax = [](float v) {
                    v = fmaxf(v, __shfl_xor(v, 1)); v = fmaxf(v, __shfl_xor(v, 2)); return v;
                };

                // widths softmax chain (2 bins per lane)
                float m_w = qmax(fmaxf(w_a, w_b));
                float ewa = __expf(w_a - m_w), ewb = __expf(w_b - m_w);
                float rsw = rcp_f(qsum(ewa + ewb));
                float bwa = oma * 1.25f + alpha * (ewa * rsw * 9.92f + 0.001f);
                float bwb = oma * 1.25f + alpha * (ewb * rsw * 9.92f + 0.001f);
                float scw = 10.0f * rcp_f(qsum(bwa + bwb));
                bwa *= scw; bwb *= scw;
                float m2w = qmax(fmaxf(bwa, bwb));
                float e2wa = __expf(bwa - m2w), e2wb = __expf(bwb - m2w);
                float rs2w = rcp_f(qsum(e2wa + e2wb));
                float wdt_a = e2wa * rs2w * 9.9992f + 1e-4f;
                float wdt_b = e2wb * rs2w * 9.9992f + 1e-4f;

                // heights softmax chain
                float m_h = qmax(fmaxf(h_a, h_b));
                float eha = __expf(h_a - m_h), ehb = __expf(h_b - m_h);
                float rsh = rcp_f(qsum(eha + ehb));
                float bha = oma * 1.25f + alpha * (eha * rsh * 9.92f + 0.001f);
                float bhb = oma * 1.25f + alpha * (ehb * rsh * 9.92f + 0.001f);
                float sch = 10.0f * rcp_f(qsum(bha + bhb));
                bha *= sch; bhb *= sch;
                float m2h = qmax(fmaxf(bha, bhb));
                float e2ha = __expf(bha - m2h), e2hb = __expf(bhb - m2h);
                float rs2h = rcp_f(qsum(e2ha + e2hb));
                float hgt_a = e2ha * rs2h * 9.9992f + 1e-4f;
                float hgt_b = e2hb * rs2h * 9.9992f + 1e-4f;

                // slopes (3 per lane: bins p, p+4, and 8 on all lanes)
                float dsl_a = softplus_f(oma + alpha * (softplus_f(d_a) + 0.001f) + dxoff) + 1e-4f;
                float dsl_b = softplus_f(oma + alpha * (softplus_f(d_b) + 0.001f) + dxoff) + 1e-4f;
                float dsl_c = softplus_f(oma + alpha * (softplus_f(d_cin) + 0.001f) + dxoff) + 1e-4f;

                // inclusive cumsums over the 8 bins (quad scan; b-half += a-total)
                float ca = wdt_a, tf;
                tf = __shfl_up(ca, 1); if (p >= 1) ca += tf;
                tf = __shfl_up(ca, 2); if (p >= 2) ca += tf;
                float cb = wdt_b;
                tf = __shfl_up(cb, 1); if (p >= 1) cb += tf;
                tf = __shfl_up(cb, 2); if (p >= 2) cb += tf;
                cb += __shfl(ca, qb + 3);

                float cha = hgt_a;
                tf = __shfl_up(cha, 1); if (p >= 1) cha += tf;
                tf = __shfl_up(cha, 2); if (p >= 2) cha += tf;
                float chb = hgt_b;
                tf = __shfl_up(chb, 1); if (p >= 1) chb += tf;
                tf = __shfl_up(chb, 2); if (p >= 2) chb += tf;
                chb += __shfl(cha, qb + 3);

                const bool inr = (zi >= -5.0f) && (zi <= 5.0f);
                const float yc = fminf(fmaxf(zi, -5.0f), 5.0f);

                // bin index: count of yp[k] <= yc for k=1..7 (CH[0..6])
                unsigned long long B1 = __ballot(yc >= cha - 5.0f);
                unsigned long long B2 = __ballot((p < 3) && (yc >= chb - 5.0f));
                unsigned long long qm = 0xFull << qb;
                int idx = __popcll(B1 & qm) + __popcll(B2 & qm);   // 0..7

                // gather knot quantities from the quad
                int s0 = qb + (idx & 3);
                float wk = (idx < 4) ? __shfl(wdt_a, s0) : __shfl(wdt_b, s0);
                float hk = (idx < 4) ? __shfl(hgt_a, s0) : __shfl(hgt_b, s0);
                int im1 = idx - 1;
                int s1 = qb + (im1 & 3);
                float cwm = (im1 < 4) ? __shfl(ca, s1) : __shfl(cb, s1);
                float chm = (im1 < 4) ? __shfl(cha, s1) : __shfl(chb, s1);
                float xk = (idx == 0) ? -5.0f : (cwm - 5.0f);
                float yk = (idx == 0) ? -5.0f : (chm - 5.0f);
                float dk = (idx < 4) ? __shfl(dsl_a, s0) : __shfl(dsl_b, s0);
                int j1 = idx + 1;
                int s2l = qb + (j1 & 3);
                float d1a = __shfl(dsl_a, s2l), d1b = __shfl(dsl_b, s2l);
                float dk1 = (j1 < 4) ? d1a : ((j1 < 8) ? d1b : dsl_c);

                // rational-quadratic inverse (redundant on the quad)
                float s_ = hk * rcp_f(wk);
                float tt = yc - yk;
                float coef = dk1 + dk - 2.0f * s_;
                float aa = hk * (s_ - dk) + tt * coef;
                float bb = hk * dk - tt * coef;
                float cc = -s_ * tt;
                float disc = bb * bb - 4.0f * aa * cc;
                float xi = 2.0f * cc * rcp_f(-bb - __builtin_amdgcn_sqrtf(disc));
                float xv = xi * wk + xk;
                float z1 = xi * (1.0f - xi);
                float den = s_ + coef * z1;
                float omxi = 1.0f - xi;
                float ld = -(2.0f * __logf(s_) +
                             __logf(dk1 * xi * xi + 2.0f * s_ * z1 + dk * omxi * omxi)
                             - 2.0f * __logf(den));

                xv_sel = inr ? xv : zi;
                ldreg += inr ? ld : 0.0f;
                if (p == 0) xs[r4 * 33 + i] = xv_sel;
            }

            // broadcast new x_i into the x A-fragment (k == i), register-only
            {
                float xnew = __shfl(xv_sel, (l & 15) << 2);
                if (g == (i >> 3)) {
#pragma unroll
                    for (int j = 0; j < 8; ++j)
                        if (j == (i & 7)) xfrag[j] = (_Float16)xnew;
                }
            }
            FENCE();
        }
    }

    FENCE();
    for (int idx = l; idx < 512; idx += 64) {
        int r = idx >> 5, c = idx & 31;
        xout[row0 * 32 + idx] = xs[r * 33 + c];
    }
    if ((l & 3) == 0) ldj[row0 + (l >> 2)] = ldreg;
}

extern "C" void kernel_launch(void* const* d_in, const int* in_sizes, int n_in,
                              void* d_out, int out_size, void* d_ws, size_t ws_size,
                              hipStream_t stream)
{
    const float* z    = (const float*)d_in[0];
    const float* W0   = (const float*)d_in[1];
    const float* b0   = (const float*)d_in[2];
    const float* W1   = (const float*)d_in[3];
    const float* b1   = (const float*)d_in[4];
    const float* Wout = (const float*)d_in[5];
    const float* bout = (const float*)d_in[6];
    const int* tstep  = (const int*)d_in[8];

    float* out  = (float*)d_out;
    float* xout = out;                 // x_fin, B x D
    float* ldj  = out + NB * DD;       // ldj, B

    _Float16* W0F   = (_Float16*)d_ws;            // 16384 halfs
    _Float16* W1F   = W0F + 16384;                // 131072 halfs
    _Float16* WoutF = W1F + 131072;               // 262144 halfs
    float* b0F  = (float*)(WoutF + 262144);       // 512 f32
    float* b1F  = b0F + 512;                      // 512 f32
    float* boutF = b1F + 512;                     // 1024 f32

    prep_kernel<<<1608, 256, 0, stream>>>(W0, b0, W1, b1, Wout, bout,
                                          W0F, W1F, WoutF, b0F, b1F, boutF);
    inv_kernel<<<NB / 16, 64, 0, stream>>>(z, W0F, W1F, WoutF, b0F, b1F, boutF,
                                           tstep, xout, ldj);
}

// Round 8
// 101.206 us; speedup vs baseline: 4.3064x; 1.3318x over previous
//
#include <hip/hip_runtime.h>

typedef _Float16 f16x8 __attribute__((ext_vector_type(8)));
typedef float f32x4 __attribute__((ext_vector_type(4)));

#define NB 8192
#define DD 32
#define PER 25
#define STRH 272   // halfs per row of h0L/h1L planes

// Compiler-only ordering fence (no hardware wait).
#define FENCE_C() do { asm volatile("" ::: "memory"); \
                       __builtin_amdgcn_sched_barrier(0); } while (0)
// Hardware LDS drain: REQUIRED at every same-wave LDS write->read handoff.
// (Round-7 lesson: ds_write -> ds_read of the same addresses without lgkmcnt(0)
// races nondeterministically; compiler order alone is NOT sufficient.)
#define FENCE_HW() do { asm volatile("s_waitcnt lgkmcnt(0)" ::: "memory"); \
                        __builtin_amdgcn_sched_barrier(0); } while (0)

__device__ __forceinline__ float rcp_f(float x) { return __builtin_amdgcn_rcpf(x); }
__device__ __forceinline__ float gelu_f(float x) {
    float a = -1.5957691216057308f * (x + 0.044715f * x * x * x);
    return x * rcp_f(1.0f + __expf(a));
}
__device__ __forceinline__ float softplus_f(float x) {
    return (x > 20.0f) ? x : __logf(1.0f + __expf(x));
}
// # hidden units with degree <= d (degs 1..8 have 9 units, 9..31 have 8)
__device__ __forceinline__ int cntf(int d) {
    return (d <= 0) ? 0 : ((d <= 8) ? 9 * d : 72 + 8 * (d - 8));
}
// original hidden index of degree-sorted position u
__device__ __forceinline__ int porig(int u) {
    int d = (u < 72) ? (u / 9 + 1) : ((u - 72) / 8 + 9);
    int s = (u < 72) ? (u % 9) : ((u - 72) % 8);
    return s * 31 + (d - 1);
}

// Pack all weights into MFMA B-fragment layout (f16, masks baked in, zero padding).
// B-frag for 16x16x32: lane l holds B[k][c] with c = l&15, k = (l>>4)*8 + j, j=0..7.
__global__ void prep_kernel(const float* __restrict__ W0, const float* __restrict__ b0,
                            const float* __restrict__ W1, const float* __restrict__ b1,
                            const float* __restrict__ Wout, const float* __restrict__ bout,
                            _Float16* __restrict__ W0F, _Float16* __restrict__ W1F,
                            _Float16* __restrict__ WoutF,
                            float* __restrict__ b0F, float* __restrict__ b1F,
                            float* __restrict__ boutF)
{
    const int total = 16384 + 131072 + 262144 + 512 + 512 + 1024;  // 411648
    for (int e = blockIdx.x * blockDim.x + threadIdx.x; e < total;
         e += gridDim.x * blockDim.x) {
        if (e < 16384) {
            int i = e >> 9, r = e & 511, lane = r >> 3, j = r & 7;
            int c = lane & 15, k = ((lane >> 4) << 3) + j;
            int nn = cntf(i) - cntf(i - 1);
            float v = 0.0f;
            if (c < nn && k < i) v = W0[k * 256 + (c * 31 + i - 1)];
            W0F[e] = (_Float16)v;
        } else if (e < 16384 + 131072) {
            int m = e - 16384;
            int i = m >> 12, r = m & 4095, kt = r >> 9, r2 = r & 511;
            int lane = r2 >> 3, j = r2 & 7;
            int c = lane & 15, kpos = kt * 32 + ((lane >> 4) << 3) + j;
            int nn = cntf(i) - cntf(i - 1), chi = cntf(i);
            float v = 0.0f;
            if (c < nn && kpos < chi) v = W1[porig(kpos) * 256 + (c * 31 + i - 1)];
            W1F[m] = (_Float16)v;
        } else if (e < 16384 + 131072 + 262144) {
            int m = e - (16384 + 131072);
            int i = m >> 13, r = m & 8191, ct = r >> 12, r2 = r & 4095;
            int kt = r2 >> 9, r3 = r2 & 511, lane = r3 >> 3, j = r3 & 7;
            int par = ct * 16 + (lane & 15), kpos = kt * 32 + ((lane >> 4) << 3) + j;
            int chi = cntf(i);
            float v = 0.0f;
            if (par < 25 && kpos < chi) v = Wout[(i * 25 + par) * 256 + porig(kpos)];
            WoutF[m] = (_Float16)v;
        } else if (e < 409600 + 512) {
            int m = e - 409600;
            int i = m >> 4, c = m & 15;
            int nn = cntf(i) - cntf(i - 1);
            b0F[m] = (c < nn) ? b0[c * 31 + i - 1] : 0.0f;
        } else if (e < 410112 + 512) {
            int m = e - 410112;
            int i = m >> 4, c = m & 15;
            int nn = cntf(i) - cntf(i - 1);
            b1F[m] = (c < nn) ? b1[c * 31 + i - 1] : 0.0f;
        } else {
            int m = e - 410624;
            int i = m >> 5, c = m & 31;
            boutF[m] = (c < 25) ? bout[i * 25 + c] : 0.0f;
        }
    }
}

// One wave per block; 16 rows per wave, all 32 AR steps, MACs on the matrix pipe.
// h0/h1 live in LDS in A-frag-readable layout (XOR-swizzled) -- no fold loops.
__global__ __launch_bounds__(64, 1) void inv_kernel(
    const float* __restrict__ z,
    const _Float16* __restrict__ W0F, const _Float16* __restrict__ W1F,
    const _Float16* __restrict__ WoutF,
    const float* __restrict__ b0F, const float* __restrict__ b1F,
    const float* __restrict__ boutF,
    const int* __restrict__ tstep_p,
    float* __restrict__ xout, float* __restrict__ ldj)
{
    __shared__ float zs[16 * 33];              // z tile  [16 rows][33] (padded)
    __shared__ float xs[16 * 33];              // x state [16 rows][33] (padded)
    __shared__ float ps[16 * 33];              // spline params per row (padded)
    __shared__ __align__(16) _Float16 h0L[16 * STRH];   // h0 state, frag layout
    __shared__ __align__(16) _Float16 h1L[16 * STRH];   // h1 state, frag layout

    const int l = threadIdx.x;
    const int c16 = l & 15;              // C/D col, B col, A row selector
    const int g = l >> 4;                // k-group
    const int row0 = blockIdx.x * 16;

    for (int idx = l; idx < 512; idx += 64) {
        int r = idx >> 5, c = idx & 31;
        zs[r * 33 + c] = z[row0 * 32 + idx];
    }
    {   // zero h0L/h1L (u32 stores); pad region included, cheap one-time
        unsigned int* p0 = (unsigned int*)h0L;
        unsigned int* p1 = (unsigned int*)h1L;
        for (int idx = l; idx < 16 * STRH / 2; idx += 64) { p0[idx] = 0u; p1[idx] = 0u; }
    }

    f16x8 xfrag;                         // A-frag of x: row=c16, k=g*8+j
#pragma unroll
    for (int j = 0; j < 8; ++j) xfrag[j] = (_Float16)0.0f;

    const float alpha = fminf(fmaxf(((float)(*tstep_p)) / 10000.0f, 0.0f), 1.0f);
    const float oma = 1.0f - alpha;
    const float dxoff = logf(expm1f(0.9999f));   // DX_OFF (once, precise)

    float ldreg = 0.0f;

    // double-buffered Phase-A weights + biases
    f16x8 wa2[2];
    float b0v2[2], b1v2[2], boA2[2], boB2[2];
    wa2[0] = *(const f16x8*)&W0F[l * 8];
    b0v2[0] = b0F[c16];
    b1v2[0] = b1F[c16];
    boA2[0] = boutF[c16];
    boB2[0] = boutF[16 + c16];

    FENCE_HW();   // zero-init / zs staging -> loop reads

#pragma unroll 1
    for (int ib = 0; ib < DD; ib += 2) {
#pragma unroll
        for (int ph = 0; ph < 2; ++ph) {
            const int i = ib + ph;
            const int clo = cntf(i - 1);
            const int chi = cntf(i);
            const int nn = chi - clo;        // 0 at i=0, else 8 or 9
            const int ip = (i + 1 < DD) ? (i + 1) : (DD - 1);

            // prefetch next step's A-weights + biases into the other buffer
            wa2[ph ^ 1] = *(const f16x8*)&W0F[ip * 512 + l * 8];
            b0v2[ph ^ 1] = b0F[ip * 16 + c16];
            b1v2[ph ^ 1] = b1F[ip * 16 + c16];
            boA2[ph ^ 1] = boutF[ip * 32 + c16];
            boB2[ph ^ 1] = boutF[ip * 32 + 16 + c16];

            // this step's B/C weight frags (first use ~1 phase later; L2 covered)
            f16x8 wb_r[8], wc_r[2][8];
#pragma unroll
            for (int kt = 0; kt < 8; ++kt)
                wb_r[kt] = *(const f16x8*)&W1F[i * 4096 + kt * 512 + l * 8];
#pragma unroll
            for (int ct = 0; ct < 2; ++ct)
#pragma unroll
                for (int kt = 0; kt < 8; ++kt)
                    wc_r[ct][kt] = *(const f16x8*)&WoutF[i * 8192 + ct * 4096 + kt * 512 + l * 8];

            // ---- Phase A: h0_new = gelu(x @ W0_i); write straight into h0L ----
            if (nn > 0) {
                f32x4 acc;
#pragma unroll
                for (int q = 0; q < 4; ++q) acc[q] = 0.0f;
                acc = __builtin_amdgcn_mfma_f32_16x16x32_f16(xfrag, wa2[ph], acc, 0, 0, 0);
                float bb = b0v2[ph];
                if (c16 < nn) {
                    const int col = clo + c16;
#pragma unroll
                    for (int q = 0; q < 4; ++q) {
                        int row = g * 4 + q;
                        int phys = (col & ~31) | ((col & 31) ^ (8 * (row & 3)));
                        h0L[row * STRH + phys] = (_Float16)gelu_f(acc[q] + bb);
                    }
                }
            }
            FENCE_HW();   // h0L writes -> Phase B frag reads

            // ---- Phase B: h1_new = gelu(h0_prefix @ W1_i); frags read from h0L ----
            if (nn > 0) {
                const int fbase = c16 * STRH + ((g ^ (c16 & 3)) << 3);
                f32x4 acc;
#pragma unroll
                for (int q = 0; q < 4; ++q) acc[q] = 0.0f;
#pragma unroll
                for (int kt = 0; kt < 8; ++kt) {
                    if (kt * 32 < chi) {
                        f16x8 af = *(const f16x8*)&h0L[fbase + kt * 32];
                        acc = __builtin_amdgcn_mfma_f32_16x16x32_f16(af, wb_r[kt], acc, 0, 0, 0);
                    }
                }
                float bb = b1v2[ph];
                if (c16 < nn) {
                    const int col = clo + c16;
#pragma unroll
                    for (int q = 0; q < 4; ++q) {
                        int row = g * 4 + q;
                        int phys = (col & ~31) | ((col & 31) ^ (8 * (row & 3)));
                        h1L[row * STRH + phys] = (_Float16)gelu_f(acc[q] + bb);
                    }
                }
            }
            FENCE_HW();   // h1L writes -> Phase C frag reads

            // ---- Phase C: p(16 rows x 25) = h1_prefix @ Wout_i + b_out ----
            {
                const int fbase = c16 * STRH + ((g ^ (c16 & 3)) << 3);
                f32x4 acc0, acc1;
#pragma unroll
                for (int q = 0; q < 4; ++q) { acc0[q] = 0.0f; acc1[q] = 0.0f; }
#pragma unroll
                for (int kt = 0; kt < 8; ++kt) {
                    if (kt * 32 < chi) {
                        f16x8 af = *(const f16x8*)&h1L[fbase + kt * 32];
                        acc0 = __builtin_amdgcn_mfma_f32_16x16x32_f16(af, wc_r[0][kt], acc0, 0, 0, 0);
                        acc1 = __builtin_amdgcn_mfma_f32_16x16x32_f16(af, wc_r[1][kt], acc1, 0, 0, 0);
                    }
                }
                float boA = boA2[ph], boB = boB2[ph];
#pragma unroll
                for (int q = 0; q < 4; ++q)
                    ps[(g * 4 + q) * 33 + c16] = acc0[q] + boA;
                if (16 + c16 < 25) {
#pragma unroll
                    for (int q = 0; q < 4; ++q)
                        ps[(g * 4 + q) * 33 + 16 + c16] = acc1[q] + boB;
                }
            }
            FENCE_HW();   // ps writes -> spline reads

            // ---- Spline inverse: 4 lanes per row, all 64 lanes active ----
            float xv_sel;
            {
                const int r4 = l >> 2;          // row 0..15
                const int p  = l & 3;           // sub-lane in quad
                const int qb = l & ~3;          // quad base lane

                const float* bp = &ps[r4 * 33];
                float w_a = bp[p],      w_b = bp[4 + p];
                float h_a = bp[8 + p],  h_b = bp[12 + p];
                float d_a = bp[16 + p], d_b = bp[20 + p], d_cin = bp[24];
                const float zi = zs[r4 * 33 + i];

                auto qsum = [](float v) {
                    v += __shfl_xor(v, 1); v += __shfl_xor(v, 2); return v;
                };
                auto qmax = [](float v) {
                    v = fmaxf(v, __shfl_xor(v, 1)); v = fmaxf(v, __shfl_xor(v, 2)); return v;
                };

                // widths softmax chain (2 bins per lane)
                float m_w = qmax(fmaxf(w_a, w_b));
                float ewa = __expf(w_a - m_w), ewb = __expf(w_b - m_w);
                float rsw = rcp_f(qsum(ewa + ewb));
                float bwa = oma * 1.25f + alpha * (ewa * rsw * 9.92f + 0.001f);
                float bwb = oma * 1.25f + alpha * (ewb * rsw * 9.92f + 0.001f);
                float scw = 10.0f * rcp_f(qsum(bwa + bwb));
                bwa *= scw; bwb *= scw;
                float m2w = qmax(fmaxf(bwa, bwb));
                float e2wa = __expf(bwa - m2w), e2wb = __expf(bwb - m2w);
                float rs2w = rcp_f(qsum(e2wa + e2wb));
                float wdt_a = e2wa * rs2w * 9.9992f + 1e-4f;
                float wdt_b = e2wb * rs2w * 9.9992f + 1e-4f;

                // heights softmax chain
                float m_h = qmax(fmaxf(h_a, h_b));
                float eha = __expf(h_a - m_h), ehb = __expf(h_b - m_h);
                float rsh = rcp_f(qsum(eha + ehb));
                float bha = oma * 1.25f + alpha * (eha * rsh * 9.92f + 0.001f);
                float bhb = oma * 1.25f + alpha * (ehb * rsh * 9.92f + 0.001f);
                float sch = 10.0f * rcp_f(qsum(bha + bhb));
                bha *= sch; bhb *= sch;
                float m2h = qmax(fmaxf(bha, bhb));
                float e2ha = __expf(bha - m2h), e2hb = __expf(bhb - m2h);
                float rs2h = rcp_f(qsum(e2ha + e2hb));
                float hgt_a = e2ha * rs2h * 9.9992f + 1e-4f;
                float hgt_b = e2hb * rs2h * 9.9992f + 1e-4f;

                // slopes
                float dsl_a = softplus_f(oma + alpha * (softplus_f(d_a) + 0.001f) + dxoff) + 1e-4f;
                float dsl_b = softplus_f(oma + alpha * (softplus_f(d_b) + 0.001f) + dxoff) + 1e-4f;
                float dsl_c = softplus_f(oma + alpha * (softplus_f(d_cin) + 0.001f) + dxoff) + 1e-4f;

                // inclusive cumsums over the 8 bins (quad scan; b-half += a-total)
                float ca = wdt_a, tf;
                tf = __shfl_up(ca, 1); if (p >= 1) ca += tf;
                tf = __shfl_up(ca, 2); if (p >= 2) ca += tf;
                float cb = wdt_b;
                tf = __shfl_up(cb, 1); if (p >= 1) cb += tf;
                tf = __shfl_up(cb, 2); if (p >= 2) cb += tf;
                cb += __shfl(ca, qb + 3);

                float cha = hgt_a;
                tf = __shfl_up(cha, 1); if (p >= 1) cha += tf;
                tf = __shfl_up(cha, 2); if (p >= 2) cha += tf;
                float chb = hgt_b;
                tf = __shfl_up(chb, 1); if (p >= 1) chb += tf;
                tf = __shfl_up(chb, 2); if (p >= 2) chb += tf;
                chb += __shfl(cha, qb + 3);

                const bool inr = (zi >= -5.0f) && (zi <= 5.0f);
                const float yc = fminf(fmaxf(zi, -5.0f), 5.0f);

                // bin index: count of yp[k] <= yc for k=1..7
                unsigned long long B1 = __ballot(yc >= cha - 5.0f);
                unsigned long long B2 = __ballot((p < 3) && (yc >= chb - 5.0f));
                unsigned long long qm = 0xFull << qb;
                int idx = __popcll(B1 & qm) + __popcll(B2 & qm);   // 0..7

                // gather knot quantities from the quad
                int s0 = qb + (idx & 3);
                float wk = (idx < 4) ? __shfl(wdt_a, s0) : __shfl(wdt_b, s0);
                float hk = (idx < 4) ? __shfl(hgt_a, s0) : __shfl(hgt_b, s0);
                int im1 = idx - 1;
                int s1 = qb + (im1 & 3);
                float cwm = (im1 < 4) ? __shfl(ca, s1) : __shfl(cb, s1);
                float chm = (im1 < 4) ? __shfl(cha, s1) : __shfl(chb, s1);
                float xk = (idx == 0) ? -5.0f : (cwm - 5.0f);
                float yk = (idx == 0) ? -5.0f : (chm - 5.0f);
                float dk = (idx < 4) ? __shfl(dsl_a, s0) : __shfl(dsl_b, s0);
                int j1 = idx + 1;
                int s2l = qb + (j1 & 3);
                float d1a = __shfl(dsl_a, s2l), d1b = __shfl(dsl_b, s2l);
                float dk1 = (j1 < 4) ? d1a : ((j1 < 8) ? d1b : dsl_c);

                // rational-quadratic inverse (redundant on the quad)
                float s_ = hk * rcp_f(wk);
                float tt = yc - yk;
                float coef = dk1 + dk - 2.0f * s_;
                float aa = hk * (s_ - dk) + tt * coef;
                float bb = hk * dk - tt * coef;
                float cc = -s_ * tt;
                float disc = bb * bb - 4.0f * aa * cc;
                float xi = 2.0f * cc * rcp_f(-bb - __builtin_amdgcn_sqrtf(disc));
                float xv = xi * wk + xk;
                float z1 = xi * (1.0f - xi);
                float den = s_ + coef * z1;
                float omxi = 1.0f - xi;
                float ld = -(2.0f * __logf(s_) +
                             __logf(dk1 * xi * xi + 2.0f * s_ * z1 + dk * omxi * omxi)
                             - 2.0f * __logf(den));

                xv_sel = inr ? xv : zi;
                ldreg += inr ? ld : 0.0f;
                if (p == 0) xs[r4 * 33 + i] = xv_sel;
            }

            // broadcast new x_i into the x A-fragment (k == i), register-only
            {
                float xnew = __shfl(xv_sel, (l & 15) << 2);
                if (g == (i >> 3)) {
#pragma unroll
                    for (int j = 0; j < 8; ++j)
                        if (j == (i & 7)) xfrag[j] = (_Float16)xnew;
                }
            }
            FENCE_C();
        }
    }

    FENCE_HW();   // xs writes -> output reads
    for (int idx = l; idx < 512; idx += 64) {
        int r = idx >> 5, c = idx & 31;
        xout[row0 * 32 + idx] = xs[r * 33 + c];
    }
    if ((l & 3) == 0) ldj[row0 + (l >> 2)] = ldreg;
}

extern "C" void kernel_launch(void* const* d_in, const int* in_sizes, int n_in,
                              void* d_out, int out_size, void* d_ws, size_t ws_size,
                              hipStream_t stream)
{
    const float* z    = (const float*)d_in[0];
    const float* W0   = (const float*)d_in[1];
    const float* b0   = (const float*)d_in[2];
    const float* W1   = (const float*)d_in[3];
    const float* b1   = (const float*)d_in[4];
    const float* Wout = (const float*)d_in[5];
    const float* bout = (const float*)d_in[6];
    const int* tstep  = (const int*)d_in[8];

    float* out  = (float*)d_out;
    float* xout = out;                 // x_fin, B x D
    float* ldj  = out + NB * DD;       // ldj, B

    _Float16* W0F   = (_Float16*)d_ws;            // 16384 halfs
    _Float16* W1F   = W0F + 16384;                // 131072 halfs
    _Float16* WoutF = W1F + 131072;               // 262144 halfs
    float* b0F  = (float*)(WoutF + 262144);       // 512 f32
    float* b1F  = b0F + 512;                      // 512 f32
    float* boutF = b1F + 512;                     // 1024 f32

    prep_kernel<<<1608, 256, 0, stream>>>(W0, b0, W1, b1, Wout, bout,
                                          W0F, W1F, WoutF, b0F, b1F, boutF);
    inv_kernel<<<NB / 16, 64, 0, stream>>>(z, W0F, W1F, WoutF, b0F, b1F, boutF,
                                           tstep, xout, ldj);
}